// Round 8
// baseline (233.326 us; speedup 1.0000x reference)
//
#include <hip/hip_runtime.h>

#define NB     8192
#define HDIM   64
#define SEQ    180
#define SB     72     // bf16 LDS row stride: 144 B, 16B-aligned rows (SB=68 regressed: misaligned b128)
#define XSP    100    // xs prologue row stride (floats)

typedef __bf16 bf16x8 __attribute__((ext_vector_type(8)));
typedef float  f32x4  __attribute__((ext_vector_type(4)));

#define L2E 1.44269504088896340736f

__device__ __forceinline__ float tanh_f(float x) {
    float e = __builtin_amdgcn_exp2f((2.0f * L2E) * x);
    return 1.0f - 2.0f * __builtin_amdgcn_rcpf(1.0f + e);
}

#define MFMA __builtin_amdgcn_mfma_f32_16x16x32_bf16

// R8: software-pipelined two-tile GRU. Block = 4 waves, 32 rows = two 16-row
// tiles T0/T1, 256 blocks (1/CU, 1 wave/SIMD). Each barrier interval:
//   [ds_read + 12 gate-MFMAs for tile X (consumed NEXT interval)]
//   [transcendental epilogue for tile Y (accs from PREVIOUS interval)]
// so MFMA/ds_read latency is structurally hidden under the other tile's VALU
// work within the same wave. 8-interval macro -> all parities/duties static.
// Numerics = R7 (proven absmax 1.95e-3): h plain bf16, w_hh hi/lo split.

// epilogue: consume acc[TY], advance hprev[TY], publish state to hbuf[TY][WB]
#define EPIL(TY, WB) do {                                                     \
    f32x4 aR = acc[TY][0], aZ = acc[TY][1], aN = acc[TY][2];                  \
    __bf16* Nh = hbuf[TY][WB];                                                \
    _Pragma("unroll")                                                         \
    for (int r = 0; r < 4; ++r) {                                             \
        float eR = __builtin_amdgcn_exp2f(__builtin_fmaf(-L2E, aR[r], cR));   \
        float rg = __builtin_amdgcn_rcpf(eR + 1.0f);                          \
        float eZ = __builtin_amdgcn_exp2f(__builtin_fmaf(-L2E, aZ[r], cZ));   \
        float zg = __builtin_amdgcn_rcpf(eZ + 1.0f);                          \
        float mm = aN[r] + bnacc;                                             \
        float eN = __builtin_amdgcn_exp2f(                                    \
                       __builtin_fmaf(2.0f * L2E, rg * mm, cN));              \
        float dd = __builtin_amdgcn_rcpf(eN + 1.0f);                          \
        float ng = __builtin_fmaf(-2.0f, dd, 1.0f);                           \
        float hn = __builtin_fmaf(zg, hprev[TY][r] - ng, ng);                 \
        hprev[TY][r] = hn;                                                    \
        Nh[wroff + r * SB] = (__bf16)hn;                                      \
    }                                                                         \
} while (0)

// one interval: reads(TX,PB) ; EPIL(TY,WB) ; 12 MFMAs(TX) ; duty out ; barrier
#define INTERVAL(TX, PB, TY, WB, DUTYW, OFF, OCOND) do {                      \
    const __bf16* Hh = hbuf[TX][PB];                                          \
    bf16x8 a0 = *(const bf16x8*)(Hh + rdoff);                                 \
    bf16x8 a1 = *(const bf16x8*)(Hh + rdoff + 32);                            \
    EPIL(TY, WB);                                                             \
    f32x4 aR = MFMA(a0, whi[0][0], kZ, 0, 0, 0);                              \
    f32x4 aZ = MFMA(a0, whi[1][0], kZ, 0, 0, 0);                              \
    f32x4 aN = MFMA(a0, whi[2][0], kZ, 0, 0, 0);                              \
    aR = MFMA(a1, whi[0][1], aR, 0, 0, 0);                                    \
    aZ = MFMA(a1, whi[1][1], aZ, 0, 0, 0);                                    \
    aN = MFMA(a1, whi[2][1], aN, 0, 0, 0);                                    \
    aR = MFMA(a0, wlo[0][0], aR, 0, 0, 0);                                    \
    aZ = MFMA(a0, wlo[1][0], aZ, 0, 0, 0);                                    \
    aN = MFMA(a0, wlo[2][0], aN, 0, 0, 0);                                    \
    aR = MFMA(a1, wlo[0][1], aR, 0, 0, 0);                                    \
    aZ = MFMA(a1, wlo[1][1], aZ, 0, 0, 0);                                    \
    aN = MFMA(a1, wlo[2][1], aN, 0, 0, 0);                                    \
    acc[TX][0] = aR; acc[TX][1] = aZ; acc[TX][2] = aN;                        \
    if ((OCOND) && w == (DUTYW)) {                                            \
        f32x4 o = obias;                                                      \
        o = MFMA(a0, obhi[0], o, 0, 0, 0);                                    \
        o = MFMA(a1, obhi[1], o, 0, 0, 0);                                    \
        o = MFMA(a0, oblo[0], o, 0, 0, 0);                                    \
        o = MFMA(a1, oblo[1], o, 0, 0, 0);                                    \
        if (n16 < 2) {                                                        \
            _Pragma("unroll")                                                 \
            for (int r = 0; r < 4; ++r)                                       \
                oph[(TX) * 5760 + r * (SEQ * 2) + (OFF)] = o[r];              \
        }                                                                     \
    }                                                                         \
    __syncthreads();                                                          \
} while (0)

__global__ __launch_bounds__(256, 1) void gru_all(
        const float* __restrict__ z, const int* __restrict__ labels,
        const float* __restrict__ embed_w, const float* __restrict__ fc_w,
        const float* __restrict__ fc_b, const float* __restrict__ w_hh,
        const float* __restrict__ b_ih, const float* __restrict__ b_hh,
        const float* __restrict__ out_w, const float* __restrict__ out_b,
        float* __restrict__ out) {
    __shared__ __align__(16) __bf16 hbuf[2][2][16 * SB];  // [tile][buf]
    __shared__ __align__(16) float  xs[32 * XSP];         // h0 input, 32 rows

    const int t = threadIdx.x;
    const int w = t >> 6;          // wave 0..3
    const int l = t & 63;
    const int q = l >> 4;          // quad 0..3
    const int n16 = l & 15;
    const int jg = 16 * w + n16;   // gate column this lane owns (both tiles)
    const int bbase = blockIdx.x * 32;

    // ---- prologue A: stage x = [z, embed(labels)] for 32 rows into LDS ----
    for (int c = t; c < 32 * 24; c += 256) {    // 24 f32x4 chunks per row
        int m = c / 24, kk = (c % 24) * 4;
        f32x4 v;
        if (kk < 32) v = *(const f32x4*)(z + (size_t)(bbase + m) * 32 + kk);
        else         v = *(const f32x4*)(embed_w + labels[bbase + m] * 64 + (kk - 32));
        *(f32x4*)(xs + m * XSP + kk) = v;
    }

    // ---- persistent w_hh fragments (hi/lo split), shared by both tiles ----
    bf16x8 whi[3][2], wlo[3][2];
#pragma unroll
    for (int g = 0; g < 3; ++g) {
        const float* pr = w_hh + (g * 64 + jg) * HDIM;
#pragma unroll
        for (int ks = 0; ks < 2; ++ks) {
            const float* p = pr + ks * 32 + q * 8;
            f32x4 va = *(const f32x4*)(p);
            f32x4 vb = *(const f32x4*)(p + 4);
#pragma unroll
            for (int j2 = 0; j2 < 4; ++j2) {
                __bf16 hiA = (__bf16)va[j2];
                whi[g][ks][j2] = hiA;
                wlo[g][ks][j2] = (__bf16)(va[j2] - (float)hiA);
                __bf16 hiB = (__bf16)vb[j2];
                whi[g][ks][4 + j2] = hiB;
                wlo[g][ks][4 + j2] = (__bf16)(vb[j2] - (float)hiB);
            }
        }
    }

    // ---- output-head B fragments ----
    bf16x8 obhi[2], oblo[2];
#pragma unroll
    for (int ks = 0; ks < 2; ++ks) {
        f32x4 va = {0.f, 0.f, 0.f, 0.f}, vb = {0.f, 0.f, 0.f, 0.f};
        if (n16 < 2) {
            va = *(const f32x4*)(out_w + n16 * 64 + ks * 32 + q * 8);
            vb = *(const f32x4*)(out_w + n16 * 64 + ks * 32 + q * 8 + 4);
        }
#pragma unroll
        for (int j2 = 0; j2 < 4; ++j2) {
            __bf16 hiA = (__bf16)va[j2];
            obhi[ks][j2] = hiA;
            oblo[ks][j2] = (__bf16)(va[j2] - (float)hiA);
            __bf16 hiB = (__bf16)vb[j2];
            obhi[ks][4 + j2] = hiB;
            oblo[ks][4 + j2] = (__bf16)(vb[j2] - (float)hiB);
        }
    }
    const float bo = (n16 == 0) ? out_b[0] : (n16 == 1) ? out_b[1] : 0.f;
    const f32x4 obias = {bo, bo, bo, bo};
    const f32x4 kZ = {0.f, 0.f, 0.f, 0.f};

    const float cR    = -L2E * (b_ih[jg] + b_hh[jg]);
    const float cZ    = -L2E * (b_ih[64 + jg] + b_hh[64 + jg]);
    const float bnacc = b_hh[128 + jg];
    const float cN    = 2.0f * L2E * b_ih[128 + jg];

    const int rdoff = n16 * SB + q * 8;    // A-frag element offset (16B-aligned)
    const int wroff = (4 * q) * SB + jg;   // state-write element offset
    float* oph = out + (size_t)(bbase + 4 * q) * (SEQ * 2) + n16;  // T0; T1 = +5760

    __syncthreads();   // xs ready

    // ---- prologue B: h0 = tanh(fc_b + fc_w . x) for both tiles ----
    float hprev[2][4];
    {
        float a[2][4];
#pragma unroll
        for (int tl = 0; tl < 2; ++tl)
#pragma unroll
            for (int r = 0; r < 4; ++r) a[tl][r] = fc_b[jg];
        const float* wr = fc_w + jg * 96;
        for (int kc = 0; kc < 24; ++kc) {
            f32x4 wv = *(const f32x4*)(wr + kc * 4);
#pragma unroll
            for (int tl = 0; tl < 2; ++tl)
#pragma unroll
                for (int r = 0; r < 4; ++r) {
                    f32x4 xv = *(const f32x4*)(xs + (16 * tl + 4 * q + r) * XSP + kc * 4);
                    a[tl][r] += wv[0] * xv[0] + wv[1] * xv[1] + wv[2] * xv[2] + wv[3] * xv[3];
                }
        }
#pragma unroll
        for (int tl = 0; tl < 2; ++tl)
#pragma unroll
            for (int r = 0; r < 4; ++r) {
                float h = tanh_f(a[tl][r]);
                hprev[tl][r] = h;
                hbuf[tl][0][wroff + r * SB] = (__bf16)h;
            }
    }
    __syncthreads();   // state 0 of both tiles published in buf 0

    f32x4 acc[2][3];

    // ---- prime: MFMA T1 state 0 (accs consumed at d0's EPIL) ----
    {
        const __bf16* Hh = hbuf[1][0];
        bf16x8 a0 = *(const bf16x8*)(Hh + rdoff);
        bf16x8 a1 = *(const bf16x8*)(Hh + rdoff + 32);
        f32x4 aR = MFMA(a0, whi[0][0], kZ, 0, 0, 0);
        f32x4 aZ = MFMA(a0, whi[1][0], kZ, 0, 0, 0);
        f32x4 aN = MFMA(a0, whi[2][0], kZ, 0, 0, 0);
        aR = MFMA(a1, whi[0][1], aR, 0, 0, 0);
        aZ = MFMA(a1, whi[1][1], aZ, 0, 0, 0);
        aN = MFMA(a1, whi[2][1], aN, 0, 0, 0);
        aR = MFMA(a0, wlo[0][0], aR, 0, 0, 0);
        aZ = MFMA(a0, wlo[1][0], aZ, 0, 0, 0);
        aN = MFMA(a0, wlo[2][0], aN, 0, 0, 0);
        aR = MFMA(a1, wlo[0][1], aR, 0, 0, 0);
        aZ = MFMA(a1, wlo[1][1], aZ, 0, 0, 0);
        aN = MFMA(a1, wlo[2][1], aN, 0, 0, 0);
        acc[1][0] = aR; acc[1][1] = aZ; acc[1][2] = aN;
    }

    // 45 macros x 8 intervals; each tile advances 4 steps per macro.
    for (int u = 0; u < 45; ++u) {
        INTERVAL(0, 0, 1, 1, 0, -2, u > 0);   // d0: MFMA T0 s=4u,   epil T1 s=4u
        INTERVAL(1, 1, 0, 1, 1,  0, 1);       // d1: MFMA T1 s=4u+1, epil T0 s=4u
        INTERVAL(0, 1, 1, 0, 1,  0, 1);       // d2
        INTERVAL(1, 0, 0, 0, 2,  2, 1);       // d3
        INTERVAL(0, 0, 1, 1, 2,  2, 1);       // d4
        INTERVAL(1, 1, 0, 1, 3,  4, 1);       // d5
        INTERVAL(0, 1, 1, 0, 3,  4, 1);       // d6
        INTERVAL(1, 0, 0, 0, 0,  6, 1);       // d7 (at u=44: T1 out row 179; gate-MFMAs unused)
        oph += 8;   // 4 steps x 2 output cols
    }

    // ---- tail: T0 output row 179 from state 180 (T0.buf0, written at d7) ----
    if (w == 1) {
        const __bf16* Hh = hbuf[0][0];
        bf16x8 a0 = *(const bf16x8*)(Hh + rdoff);
        bf16x8 a1 = *(const bf16x8*)(Hh + rdoff + 32);
        f32x4 o = obias;
        o = MFMA(a0, obhi[0], o, 0, 0, 0);
        o = MFMA(a1, obhi[1], o, 0, 0, 0);
        o = MFMA(a0, oblo[0], o, 0, 0, 0);
        o = MFMA(a1, oblo[1], o, 0, 0, 0);
        if (n16 < 2) {
#pragma unroll
            for (int r = 0; r < 4; ++r)
                oph[r * (SEQ * 2) - 2] = o[r];
        }
    }
}

extern "C" void kernel_launch(void* const* d_in, const int* in_sizes, int n_in,
                              void* d_out, int out_size, void* d_ws, size_t ws_size,
                              hipStream_t stream) {
    (void)in_sizes; (void)n_in; (void)out_size; (void)d_ws; (void)ws_size;
    const float* z       = (const float*)d_in[0];
    const int*   labels  = (const int*)d_in[1];
    const float* embed_w = (const float*)d_in[2];
    const float* fc_w    = (const float*)d_in[3];
    const float* fc_b    = (const float*)d_in[4];
    // d_in[5] = w_ih: unused (GRU input is all zeros; b_ih carries the effect)
    const float* w_hh    = (const float*)d_in[6];
    const float* b_ih    = (const float*)d_in[7];
    const float* b_hh    = (const float*)d_in[8];
    const float* out_w   = (const float*)d_in[9];
    const float* out_b   = (const float*)d_in[10];
    float* out = (float*)d_out;

    gru_all<<<NB / 32, 256, 0, stream>>>(z, labels, embed_w, fc_w, fc_b,
                                         w_hh, b_ih, b_hh, out_w, out_b, out);
}